// Round 10
// baseline (322.945 us; speedup 1.0000x reference)
//
#include <hip/hip_runtime.h>
#include <math.h>

// Problem constants
#define B64 64
#define IN_SH 10000
#define EXP_SH 53
#define HID 1500
#define NPAD1 1536          // padded N for gemm1 accumulator
#define NBC 2048
#define K2 1553
#define KS1 40              // split-K chunks gemm1 (24*40 = 960 blocks)
#define KST1 8              // 8 steps of 32 => kchunk 256
#define KS2 13              // 32*13 = 416 blocks
#define KST2 4              // 4 steps of 32 => kchunk 128
#define CMCH 32             // colmax row chunks
#define LDSF 2080           // 32 rows * 65 floats (pad +1 breaks conflicts)

using short8  = __attribute__((ext_vector_type(8))) short;
using floatx4 = __attribute__((ext_vector_type(4))) float;
using uintx4  = __attribute__((ext_vector_type(4))) unsigned int;

__device__ __forceinline__ unsigned short f2bf(float f) {
    unsigned u = __float_as_uint(f);
    u += 0x7fffu + ((u >> 16) & 1u);   // RNE
    return (unsigned short)(u >> 16);
}

// B-fragment-order activation buffer:
//   Bf[((step*4 + sgrp)*64 + lane)*8 + j] = act[b = sgrp*16 + (lane&15)][k = step*32 + (lane>>4)*8 + j]

// Shared combine logic: X[n] = n<HID ? gelu(hpre[n][b]+b1[n]) : (n<HID+EXP ? expx : 0)
// When AGENTLOAD, hpre is read with agent-scope atomic loads (coherent point).
template<bool AGENTLOAD>
__device__ __forceinline__ void combine_tuple(
    int t, const float* __restrict__ hpre, const float* __restrict__ b1,
    const float* __restrict__ expx, unsigned short* __restrict__ Xf)
{
    int lane = t & 63;
    int sgrp = (t >> 6) & 3;
    int step = t >> 8;
    int q    = lane >> 4;
    int l15  = lane & 15;
    int b    = sgrp * 16 + l15;
    int kb   = step * 32 + q * 8;
    unsigned int o[4];
    #pragma unroll
    for (int i = 0; i < 4; i++) {
        unsigned int lohi[2];
        #pragma unroll
        for (int h = 0; h < 2; h++) {
            int n = kb + 2 * i + h;
            float v = 0.f;
            if (n < HID) {
                float s;
                if (AGENTLOAD)
                    s = __hip_atomic_load(&hpre[(size_t)n * 64 + b],
                                          __ATOMIC_RELAXED, __HIP_MEMORY_SCOPE_AGENT);
                else
                    s = hpre[(size_t)n * 64 + b];
                s += b1[n];
                v = 0.5f * s * (1.0f + erff(s * 0.70710678118654752f));
            } else if (n < HID + EXP_SH) {
                v = expx[b * EXP_SH + (n - HID)];
            }
            lohi[h] = f2bf(v);
        }
        o[i] = lohi[0] | (lohi[1] << 16);
    }
    uintx4 v; v.x = o[0]; v.y = o[1]; v.z = o[2]; v.w = o[3];
    *(uintx4*)(Xf + (size_t)t * 8) = v;
}

// Node 1: [0,320) build gosBf; [320,576) hpo colmax; [576,585) zero acc+counters;
//         [585] Xf tail (steps 48..51: exp_x remainder + zero pad — no gemm1 dep).
__global__ __launch_bounds__(256) void prep_k(const float* __restrict__ g,
                                              unsigned short* __restrict__ gosBf,
                                              const float* __restrict__ M,
                                              float* __restrict__ cm,
                                              float* __restrict__ accz,
                                              const float* __restrict__ expx,
                                              unsigned short* __restrict__ Xf) {
    int bi = blockIdx.x;
    if (bi < 320) {
        int t    = bi * 256 + threadIdx.x;   // [0, 81920)
        int lane = t & 63;
        int sgrp = (t >> 6) & 3;
        int step = t >> 8;                   // [0, 320)
        int q    = lane >> 4;
        int l15  = lane & 15;
        int b    = sgrp * 16 + l15;
        int k0   = step * 32 + q * 8;
        const float* p = g + (size_t)b * IN_SH + k0;
        unsigned int o[4];
        #pragma unroll
        for (int i = 0; i < 4; i++) {
            float lo = (k0 + 2 * i     < IN_SH) ? p[2 * i]     : 0.f;
            float hi = (k0 + 2 * i + 1 < IN_SH) ? p[2 * i + 1] : 0.f;
            o[i] = (unsigned)f2bf(lo) | ((unsigned)f2bf(hi) << 16);
        }
        uintx4 v; v.x = o[0]; v.y = o[1]; v.z = o[2]; v.w = o[3];
        *(uintx4*)(gosBf + (size_t)t * 8) = v;
    } else if (bi < 576) {
        int ci = bi - 320;                    // 256 blocks: 8 j-tiles x 32 row-chunks
        int j  = (ci & 7) * 256 + threadIdx.x;
        int i0 = (ci >> 3) * 64;
        float m = 0.0f;
        #pragma unroll 16
        for (int i = i0; i < i0 + 64; i++)
            m = fmaxf(m, M[(size_t)i * NBC + j]);
        cm[(ci >> 3) * NBC + j] = m;
    } else if (bi < 585) {
        // zero 230400 floats (hpre + logits + counters): 9 blocks * 256 thr * 25 float4
        int t = (bi - 576) * 256 + threadIdx.x;   // [0, 2304)
        floatx4 z = (floatx4){0.f, 0.f, 0.f, 0.f};
        #pragma unroll
        for (int i = 0; i < 25; i++)
            *(floatx4*)(accz + (size_t)(i * 2304 + t) * 4) = z;
    } else {
        // Xf tuples [12288, 13312): steps 48..51, n >= 1536 (expx tail / zero pad)
        #pragma unroll
        for (int it = 0; it < 4; it++)
            combine_tuple<false>(12288 + it * 256 + (int)threadIdx.x,
                                 nullptr, nullptr, expx, Xf);
    }
}

__device__ __forceinline__ void load_b4(const unsigned short* __restrict__ bf,
                                        int stg, uintx4 bv[4]) {
    #pragma unroll
    for (int s = 0; s < 4; s++)
        bv[s] = *(const uintx4*)(bf + (size_t)(stg * 4 + s) * 512);
}

// stage one 32k x 64n W patch into registers (coalesced dwordx4 rows; guarded on edge)
__device__ __forceinline__ void stage_load(
    const float* __restrict__ W, int kg0, int n0, int N, int K, int ldw,
    int tid, bool fast, float r[2][4])
{
    #pragma unroll
    for (int i = 0; i < 2; i++) {
        int kl = (tid >> 4) + 16 * i;          // row 0..31
        int kg = kg0 + kl;
        int n  = n0 + (tid & 15) * 4;
        if (fast) {
            floatx4 v = *(const floatx4*)(W + (size_t)kg * ldw + n);
            r[i][0] = v.x; r[i][1] = v.y; r[i][2] = v.z; r[i][3] = v.w;
        } else {
            #pragma unroll
            for (int j = 0; j < 4; j++)
                r[i][j] = (kg < K && n + j < N) ? W[(size_t)kg * ldw + n + j] : 0.f;
        }
    }
}

__device__ __forceinline__ void stage_write(float* __restrict__ ldsb, int tid,
                                            const float r[2][4]) {
    #pragma unroll
    for (int i = 0; i < 2; i++) {
        int kl  = (tid >> 4) + 16 * i;
        int seg = tid & 15;
        floatx4 v; v.x = r[i][0]; v.y = r[i][1]; v.z = r[i][2]; v.w = r[i][3];
        *(floatx4*)(ldsb + kl * 65 + seg * 4) = v;
    }
}

// r8 gemm core (best measured): LDS double-buffered W staging, 1 barrier/step,
// B-activations from fragment-order global buffer, fp32 atomicAdd epilogue.
template<int KSTEPS>
__device__ __forceinline__ void gemm_core(
    const float* __restrict__ W, const unsigned short* __restrict__ Bf,
    float* __restrict__ accbuf, int N, int K, int ldw, int bx, int by, int tid,
    float (*lds)[LDSF])
{
    int w    = tid >> 6;
    int lane = tid & 63;
    int q    = lane >> 4;
    int l15  = lane & 15;
    int n0   = bx * 64;
    int k0   = by * (KSTEPS * 32);
    bool fast = (n0 + 64 <= N) && (k0 + KSTEPS * 32 <= K);

    const unsigned short* bf = Bf + (size_t)(by * KSTEPS * 4) * 512 + (size_t)lane * 8;

    floatx4 acc[4];
    #pragma unroll
    for (int s = 0; s < 4; s++) acc[s] = (floatx4){0.f, 0.f, 0.f, 0.f};

    float r[2][4];
    stage_load(W, k0, n0, N, K, ldw, tid, fast, r);
    stage_write(lds[0], tid, r);

    uintx4 bv[2][4];
    load_b4(bf, 0, bv[0]);
    if (KSTEPS > 1) load_b4(bf, 1, bv[1]);

    #pragma unroll
    for (int st = 0; st < KSTEPS; st++) {
        if (st + 1 < KSTEPS)
            stage_load(W, k0 + (st + 1) * 32, n0, N, K, ldw, tid, fast, r);
        uintx4 bt[4];
        if (st + 2 < KSTEPS) load_b4(bf, st + 2, bt);

        __syncthreads();                        // lds[st&1] writes visible

        const float* lb = lds[st & 1];
        short8 af;
        #pragma unroll
        for (int j = 0; j < 8; j++)
            af[j] = (short)f2bf(lb[(q * 8 + j) * 65 + 16 * w + l15]);

        const int p = st & 1;                   // compile-time after unroll
        #pragma unroll
        for (int s = 0; s < 4; s++) {
            short8 bf8 = __builtin_bit_cast(short8, bv[p][s]);
            acc[s] = __builtin_amdgcn_mfma_f32_16x16x32_bf16(af, bf8, acc[s], 0, 0, 0);
        }

        if (st + 1 < KSTEPS)
            stage_write(lds[(st + 1) & 1], tid, r);
        if (st + 2 < KSTEPS) {
            #pragma unroll
            for (int s = 0; s < 4; s++) bv[p][s] = bt[s];
        }
    }

    // D lane mapping: col=lane&15 (batch within group s), row=q*4+r (n offset)
    int nrow = n0 + 16 * w + q * 4;
    #pragma unroll
    for (int s = 0; s < 4; s++) {
        #pragma unroll
        for (int rr = 0; rr < 4; rr++)
            atomicAdd(&accbuf[(size_t)(nrow + rr) * 64 + s * 16 + l15], acc[s][rr]);
    }
}

// last-block-done detection: returns true for the final finishing block of group bx
__device__ __forceinline__ bool last_done(int* cnt, int bx, int target, int* flag) {
    __threadfence();
    if (threadIdx.x == 0) {
        int old = __hip_atomic_fetch_add(&cnt[bx], 1, __ATOMIC_ACQ_REL,
                                         __HIP_MEMORY_SCOPE_AGENT);
        *flag = (old == target - 1);
    }
    __syncthreads();
    return *flag != 0;
}

// Node 2: GEMM1 + fused combine epilogue (last split-K block per bx does
// bias+GELU+concat for its 64 n-columns -> Xf steps [bx*2, bx*2+2)).
__global__ __launch_bounds__(256) void gemm1_k(
    const float* __restrict__ W1, const unsigned short* __restrict__ gosBf,
    float* __restrict__ hpre, const float* __restrict__ b1,
    const float* __restrict__ expx, unsigned short* __restrict__ Xf,
    int* __restrict__ c1)
{
    __shared__ float lds[2][LDSF];
    __shared__ int flag;
    int bx = blockIdx.x;
    gemm_core<KST1>(W1, gosBf, hpre, HID, IN_SH, HID, bx, blockIdx.y,
                    threadIdx.x, lds);
    if (last_done(c1, bx, KS1, &flag)) {
        #pragma unroll
        for (int it = 0; it < 2; it++)
            combine_tuple<true>(bx * 512 + it * 256 + (int)threadIdx.x,
                                hpre, b1, expx, Xf);
    }
}

// Node 3: GEMM2 + fused final epilogue (last split-K block per bx does
// bias+sigmoid+*colmax for its 64 j-columns).
__global__ __launch_bounds__(256) void gemm2_k(
    const float* __restrict__ W2, const unsigned short* __restrict__ Xf,
    float* __restrict__ logits, const float* __restrict__ b2,
    const float* __restrict__ cm, float* __restrict__ out,
    int* __restrict__ c2)
{
    __shared__ float lds[2][LDSF];
    __shared__ int flag;
    int bx = blockIdx.x;
    gemm_core<KST2>(W2, Xf, logits, NBC, K2, NBC, bx, blockIdx.y,
                    threadIdx.x, lds);
    if (last_done(c2, bx, KS2, &flag)) {
        int j  = bx * 64 + ((int)threadIdx.x & 63);
        int b0 = ((int)threadIdx.x >> 6) * 16;
        float m = 0.f;
        #pragma unroll
        for (int c = 0; c < CMCH; c++) m = fmaxf(m, cm[c * NBC + j]);
        float bj = b2[j];
        #pragma unroll
        for (int i = 0; i < 16; i++) {
            int b = b0 + i;
            float s = __hip_atomic_load(&logits[(size_t)j * 64 + b],
                                        __ATOMIC_RELAXED, __HIP_MEMORY_SCOPE_AGENT) + bj;
            float sig = 1.0f / (1.0f + expf(-s));
            out[(size_t)b * NBC + j] = sig * m;
        }
    }
}

extern "C" void kernel_launch(void* const* d_in, const int* in_sizes, int n_in,
                              void* d_out, int out_size, void* d_ws, size_t ws_size,
                              hipStream_t stream) {
    const float* gos  = (const float*)d_in[0];
    const float* expx = (const float*)d_in[1];
    const float* W1   = (const float*)d_in[2];
    const float* b1   = (const float*)d_in[3];
    const float* W2   = (const float*)d_in[4];
    const float* b2   = (const float*)d_in[5];
    const float* hpo  = (const float*)d_in[6];
    float* out = (float*)d_out;

    // workspace layout (16B-aligned offsets)
    char* ws = (char*)d_ws;
    unsigned short* gosBf = (unsigned short*)ws;           // 320*4*64*8*2 = 1,310,720
    float* hpre   = (float*)(ws + 1310720);                // 98304 f  = 393,216 B
    float* logits = (float*)(ws + 1310720 + 393216);       // 131072 f = 524,288 B
    int*   c1     = (int*)  (ws + 2228224);                // 24 ints (in 1024-f zero pad)
    int*   c2     = c1 + 32;                               // 32 ints
    unsigned short* Xf = (unsigned short*)(ws + 2232320);  // 52*4*64*8*2 = 212,992
    float* cm     = (float*)(ws + 2445312);                // 32*2048*4   = 262,144
    // total ~2.7 MB

    // 1) gosBf | hpo colmax | zero hpre+logits+counters | Xf tail (steps 48..51)
    prep_k<<<586, 256, 0, stream>>>(gos, gosBf, hpo, cm, hpre, expx, Xf);

    // 2) GEMM1 (atomic split-K) + combine epilogue in last-done blocks
    gemm1_k<<<dim3(NPAD1 / 64, KS1), 256, 0, stream>>>(W1, gosBf, hpre, b1, expx, Xf, c1);

    // 3) GEMM2 (atomic split-K) + final epilogue in last-done blocks
    gemm2_k<<<dim3(NBC / 64, KS2), 256, 0, stream>>>(W2, Xf, logits, b2, cm, out, c2);
}

// Round 11
// 162.262 us; speedup vs baseline: 1.9903x; 1.9903x over previous
//
#include <hip/hip_runtime.h>
#include <math.h>

// Problem constants
#define B64 64
#define IN_SH 10000
#define EXP_SH 53
#define HID 1500
#define NPAD1 1536          // padded N for gemm1 accumulator
#define NBC 2048
#define K2 1553
#define KS1 40              // split-K chunks gemm1 (24*40 = 960 blocks)
#define KST1 8              // 8 steps of 32 => kchunk 256
#define KS2 13              // 32*13 = 416 blocks
#define KST2 4              // 4 steps of 32 => kchunk 128
#define CMCH 32             // colmax row chunks
#define WLDS 640            // dwords per wave LDS buffer (32 rows * 20)

using short8  = __attribute__((ext_vector_type(8))) short;
using floatx4 = __attribute__((ext_vector_type(4))) float;
using uintx4  = __attribute__((ext_vector_type(4))) unsigned int;

__device__ __forceinline__ unsigned short f2bf(float f) {
    unsigned u = __float_as_uint(f);
    u += 0x7fffu + ((u >> 16) & 1u);   // RNE
    return (unsigned short)(u >> 16);
}

// B-fragment-order activation buffer:
//   Bf[((step*4 + sgrp)*64 + lane)*8 + j] = act[b = sgrp*16 + (lane&15)][k = step*32 + (lane>>4)*8 + j]

// Node 1: [0,320) build gosBf; [320,576) hpo partial column max; [576,584) zero accumulators.
__global__ __launch_bounds__(256) void prep_k(const float* __restrict__ g,
                                              unsigned short* __restrict__ gosBf,
                                              const float* __restrict__ M,
                                              float* __restrict__ cm,
                                              float* __restrict__ accz) {
    int bi = blockIdx.x;
    if (bi < 320) {
        int t    = bi * 256 + threadIdx.x;   // [0, 81920)
        int lane = t & 63;
        int sgrp = (t >> 6) & 3;
        int step = t >> 8;                   // [0, 320)
        int q    = lane >> 4;
        int l15  = lane & 15;
        int b    = sgrp * 16 + l15;
        int k0   = step * 32 + q * 8;
        const float* p = g + (size_t)b * IN_SH + k0;
        unsigned int o[4];
        #pragma unroll
        for (int i = 0; i < 4; i++) {
            float lo = (k0 + 2 * i     < IN_SH) ? p[2 * i]     : 0.f;
            float hi = (k0 + 2 * i + 1 < IN_SH) ? p[2 * i + 1] : 0.f;
            o[i] = (unsigned)f2bf(lo) | ((unsigned)f2bf(hi) << 16);
        }
        uintx4 v; v.x = o[0]; v.y = o[1]; v.z = o[2]; v.w = o[3];
        *(uintx4*)(gosBf + (size_t)t * 8) = v;
    } else if (bi < 576) {
        int ci = bi - 320;                    // 256 blocks: 8 j-tiles x 32 row-chunks
        int j  = (ci & 7) * 256 + threadIdx.x;
        int i0 = (ci >> 3) * 64;
        float m = 0.0f;
        #pragma unroll 16
        for (int i = i0; i < i0 + 64; i++)
            m = fmaxf(m, M[(size_t)i * NBC + j]);
        cm[(ci >> 3) * NBC + j] = m;
    } else {
        // zero 229376 floats (hpre + logits contiguous): 8 blocks * 256 thr * 28 float4
        int t = (bi - 576) * 256 + threadIdx.x;
        floatx4 z = (floatx4){0.f, 0.f, 0.f, 0.f};
        #pragma unroll
        for (int i = 0; i < 28; i++)
            *(floatx4*)(accz + (size_t)(i * 2048 + t) * 4) = z;
    }
}

__device__ __forceinline__ void load_b4(const unsigned short* __restrict__ bf,
                                        int stg, uintx4 bv[4]) {
    #pragma unroll
    for (int s = 0; s < 4; s++)
        bv[s] = *(const uintx4*)(bf + (size_t)(stg * 4 + s) * 512);
}

// Barrier-free MFMA GEMM core. Each wave stages its own 16-column W sub-tile
// into a wave-private LDS double buffer (intra-wave DS ops are in-order, so
// no __syncthreads is needed anywhere) -> compiler emits fine-grained
// vmcnt(N)/lgkmcnt(N) instead of the vmcnt(0)-before-barrier drain.
// fp32 atomicAdd accumulation into accbuf[n*64+b].
template<int KSTEPS>
__device__ __forceinline__ void gemm_core(
    const float* __restrict__ W, const unsigned short* __restrict__ Bf,
    float* __restrict__ accbuf, int N, int K, int ldw, int bx, int by, int tid,
    float* __restrict__ ldsw)   // this wave's 2*WLDS-dword region
{
    int lane = tid & 63;
    int q    = lane >> 4;
    int l15  = lane & 15;
    int n0   = bx * 64 + 16 * (tid >> 6);   // this wave's 16 columns
    int k0   = by * (KSTEPS * 32);
    bool fast = (n0 + 16 <= N) && (k0 + KSTEPS * 32 <= K);
    int kl  = lane >> 2;                    // 0..15  (staging row)
    int c4  = (lane & 3) * 4;               // staging col offset

    const unsigned short* bf = Bf + (size_t)(by * KSTEPS * 4) * 512 + (size_t)lane * 8;

    floatx4 acc[4];
    #pragma unroll
    for (int s = 0; s < 4; s++) acc[s] = (floatx4){0.f, 0.f, 0.f, 0.f};

    floatx4 g[2][2];   // [stage parity][row half]

    // global load of one 32k x 16n wave-tile (two dwordx4 per lane)
    #define GLB(st, slot)                                                        \
        {                                                                        \
            int kb_ = k0 + (st) * 32;                                            \
            _Pragma("unroll")                                                    \
            for (int i_ = 0; i_ < 2; i_++) {                                     \
                int kg_ = kb_ + kl + 16 * i_;                                    \
                if (fast) {                                                      \
                    g[slot][i_] = *(const floatx4*)(W + (size_t)kg_ * ldw + n0 + c4); \
                } else {                                                         \
                    _Pragma("unroll")                                            \
                    for (int j_ = 0; j_ < 4; j_++)                               \
                        g[slot][i_][j_] = (kg_ < K && n0 + c4 + j_ < N)          \
                            ? W[(size_t)kg_ * ldw + n0 + c4 + j_] : 0.f;         \
                }                                                                \
            }                                                                    \
        }
    // write slot -> wave-private LDS buffer (stride-20 rows, b128)
    #define LWR(buf, slot)                                                       \
        {                                                                        \
            _Pragma("unroll")                                                    \
            for (int i_ = 0; i_ < 2; i_++)                                       \
                *(floatx4*)(ldsw + (buf) * WLDS + (kl + 16 * i_) * 20 + c4) = g[slot][i_]; \
        }

    GLB(0, 0);
    if (KSTEPS > 1) GLB(1, 1);
    LWR(0, 0);

    uintx4 bv[2][4];
    load_b4(bf, 0, bv[0]);
    if (KSTEPS > 1) load_b4(bf, 1, bv[1]);

    #pragma unroll
    for (int st = 0; st < KSTEPS; st++) {
        const int s = st & 1;                     // compile-time after unroll
        const float* lb = ldsw + s * WLDS;

        // 1) fragment reads for step st (LDS buf s, written at st-1 / pre-loop)
        short8 af;
        #pragma unroll
        for (int j = 0; j < 8; j++)
            af[j] = (short)f2bf(lb[(q * 8 + j) * 20 + l15]);

        // 2) issue next-next global loads (W into freed slot s, B into bt)
        uintx4 bt[4];
        if (st + 2 < KSTEPS) {
            GLB(st + 2, s);
            load_b4(bf, st + 2, bt);
        }

        // 3) MFMAs for step st
        #pragma unroll
        for (int m = 0; m < 4; m++) {
            short8 bf8 = __builtin_bit_cast(short8, bv[s][m]);
            acc[m] = __builtin_amdgcn_mfma_f32_16x16x32_bf16(af, bf8, acc[m], 0, 0, 0);
        }

        // 4) stage st+1 into the other LDS buffer (in-order DS: safe, no barrier)
        if (st + 1 < KSTEPS) LWR(1 - s, 1 - s);
        if (st + 2 < KSTEPS) {
            #pragma unroll
            for (int m = 0; m < 4; m++) bv[s][m] = bt[m];
        }
    }
    #undef GLB
    #undef LWR

    // D lane mapping: col=lane&15 (batch within group s), row=q*4+r (n offset)
    int nrow = n0 + q * 4;
    #pragma unroll
    for (int s = 0; s < 4; s++) {
        #pragma unroll
        for (int rr = 0; rr < 4; rr++)
            atomicAdd(&accbuf[(size_t)(nrow + rr) * 64 + s * 16 + l15], acc[s][rr]);
    }
}

// Node 2: GEMM1  h_pre += gos @ W1  (N=1500, K=10000)
__global__ __launch_bounds__(256) void gemm1_k(
    const float* __restrict__ W1, const unsigned short* __restrict__ gosBf,
    float* __restrict__ hpre)
{
    __shared__ float lds[4 * 2 * WLDS];
    gemm_core<KST1>(W1, gosBf, hpre, HID, IN_SH, HID, blockIdx.x, blockIdx.y,
                    threadIdx.x, lds + (threadIdx.x >> 6) * (2 * WLDS));
}

// Node 4: GEMM2  logits += X @ W2  (N=2048, K=1553)
__global__ __launch_bounds__(256) void gemm2_k(
    const float* __restrict__ W2, const unsigned short* __restrict__ Xf,
    float* __restrict__ logits)
{
    __shared__ float lds[4 * 2 * WLDS];
    gemm_core<KST2>(W2, Xf, logits, NBC, K2, NBC, blockIdx.x, blockIdx.y,
                    threadIdx.x, lds + (threadIdx.x >> 6) * (2 * WLDS));
}

// Node 3: bias + exact GELU on h_pre, concat exp_x, emit Xf in B-fragment order.
__global__ __launch_bounds__(256) void combine1(
    const float* __restrict__ hpre, const float* __restrict__ b1,
    const float* __restrict__ expx, unsigned short* __restrict__ Xf)
{
    int t    = blockIdx.x * 256 + threadIdx.x;   // [0, 13312)
    int lane = t & 63;
    int sgrp = (t >> 6) & 3;
    int step = t >> 8;                            // [0, 52)
    int q    = lane >> 4;
    int l15  = lane & 15;
    int b    = sgrp * 16 + l15;
    int kb   = step * 32 + q * 8;
    unsigned int o[4];
    #pragma unroll
    for (int i = 0; i < 4; i++) {
        unsigned int lohi[2];
        #pragma unroll
        for (int h = 0; h < 2; h++) {
            int n = kb + 2 * i + h;
            float v = 0.f;
            if (n < HID) {
                float s = hpre[(size_t)n * 64 + b] + b1[n];
                v = 0.5f * s * (1.0f + erff(s * 0.70710678118654752f));
            } else if (n < HID + EXP_SH) {
                v = expx[b * EXP_SH + (n - HID)];
            }
            lohi[h] = f2bf(v);
        }
        o[i] = lohi[0] | (lohi[1] << 16);
    }
    uintx4 v; v.x = o[0]; v.y = o[1]; v.z = o[2]; v.w = o[3];
    *(uintx4*)(Xf + (size_t)t * 8) = v;
}

// Node 5: bias + sigmoid on logits, multiply by column max (reduce 32 chunks)
__global__ __launch_bounds__(256) void final_k(
    const float* __restrict__ logits, const float* __restrict__ b2,
    const float* __restrict__ cm, float* __restrict__ out)
{
    int idx = blockIdx.x * 256 + threadIdx.x;   // 64*2048 threads
    int b = idx & 63;
    int j = idx >> 6;
    float s = logits[(size_t)j * 64 + b] + b2[j];
    float sig = 1.0f / (1.0f + expf(-s));
    float m = 0.f;
    #pragma unroll
    for (int c = 0; c < CMCH; c++) m = fmaxf(m, cm[c * NBC + j]);
    out[(size_t)b * NBC + j] = sig * m;
}

extern "C" void kernel_launch(void* const* d_in, const int* in_sizes, int n_in,
                              void* d_out, int out_size, void* d_ws, size_t ws_size,
                              hipStream_t stream) {
    const float* gos  = (const float*)d_in[0];
    const float* expx = (const float*)d_in[1];
    const float* W1   = (const float*)d_in[2];
    const float* b1   = (const float*)d_in[3];
    const float* W2   = (const float*)d_in[4];
    const float* b2   = (const float*)d_in[5];
    const float* hpo  = (const float*)d_in[6];
    float* out = (float*)d_out;

    // workspace layout (16B-aligned offsets)
    char* ws = (char*)d_ws;
    unsigned short* gosBf = (unsigned short*)ws;                   // 320*4*64*8*2 = 1,310,720
    float* hpre   = (float*)(ws + 1310720);                        // 1536*64*4    =   393,216
    float* logits = (float*)(ws + 1310720 + 393216);               // 2048*64*4    =   524,288 (contiguous with hpre)
    unsigned short* Xf = (unsigned short*)(ws + 1310720 + 393216 + 524288);  // 52*4*64*8*2 = 212,992
    float* cm = (float*)(ws + 1310720 + 393216 + 524288 + 212992); // 32*2048*4    =   262,144
    // total ~2.7 MB

    // 1) build gosBf | hpo partial column-max | zero accumulators
    prep_k<<<584, 256, 0, stream>>>(gos, gosBf, hpo, cm, hpre);

    // 2) GEMM1 (atomic split-K, barrier-free wave-private LDS staging)
    gemm1_k<<<dim3(NPAD1 / 64, KS1), 256, 0, stream>>>(W1, gosBf, hpre);

    // 3) bias + gelu + concat exp_x -> Xf (B-fragment order)
    combine1<<<52, 256, 0, stream>>>(hpre, b1, expx, Xf);

    // 4) GEMM2 (atomic split-K, barrier-free wave-private LDS staging)
    gemm2_k<<<dim3(NBC / 64, KS2), 256, 0, stream>>>(W2, Xf, logits);

    // 5) bias + sigmoid + *colmax -> out
    final_k<<<(B64 * NBC) / 256, 256, 0, stream>>>(logits, b2, cm, out);
}